// Round 1
// baseline (885.517 us; speedup 1.0000x reference)
//
#include <hip/hip_runtime.h>
#include <math.h>

#define F 512
#define H 16
#define C 40

// ---------------- graph build ----------------

__global__ void k_count(const int* __restrict__ dst, int* __restrict__ deg, int E) {
    int e = blockIdx.x * 256 + threadIdx.x;
    if (e < E) atomicAdd(&deg[dst[e]], 1);
}

__global__ void k_scan_a(const int* __restrict__ deg, int* __restrict__ bsum, int N) {
    int i = blockIdx.x * 256 + threadIdx.x;
    int v = (i < N) ? deg[i] : 0;
    #pragma unroll
    for (int off = 32; off; off >>= 1) v += __shfl_xor(v, off, 64);
    __shared__ int ws4[4];
    if ((threadIdx.x & 63) == 0) ws4[threadIdx.x >> 6] = v;
    __syncthreads();
    if (threadIdx.x == 0) bsum[blockIdx.x] = ws4[0] + ws4[1] + ws4[2] + ws4[3];
}

// single block exclusive scan of block sums (nb <= 1024)
__global__ void k_scan_b(int* bsum, int nb, int* rowptr, int N, int E) {
    __shared__ int s[1024];
    int t = threadIdx.x;
    int v = (t < nb) ? bsum[t] : 0;
    s[t] = v;
    __syncthreads();
    for (int off = 1; off < 1024; off <<= 1) {
        int add = (t >= off) ? s[t - off] : 0;
        __syncthreads();
        s[t] += add;
        __syncthreads();
    }
    if (t < nb) bsum[t] = s[t] - v;  // exclusive
    if (t == 0) rowptr[N] = E;
}

__global__ void k_scan_c(const int* __restrict__ deg, const int* __restrict__ bsum,
                         int* __restrict__ rowptr, int* __restrict__ cursor, int N) {
    int i = blockIdx.x * 256 + threadIdx.x;
    int lane = threadIdx.x & 63, wid = threadIdx.x >> 6;
    int v = (i < N) ? deg[i] : 0;
    int inc = v;
    #pragma unroll
    for (int off = 1; off < 64; off <<= 1) {
        int up = __shfl_up(inc, off, 64);
        if (lane >= off) inc += up;
    }
    __shared__ int wsum[4];
    if (lane == 63) wsum[wid] = inc;
    __syncthreads();
    int woff = 0;
    for (int w = 0; w < wid; w++) woff += wsum[w];
    if (i < N) {
        int excl = bsum[blockIdx.x] + woff + inc - v;
        rowptr[i] = excl;
        cursor[i] = excl;
    }
}

__global__ void k_fill(const int* __restrict__ src, const int* __restrict__ dst,
                       int* __restrict__ cursor, int* __restrict__ adj, int E) {
    int e = blockIdx.x * 256 + threadIdx.x;
    if (e >= E) return;
    int slot = atomicAdd(&cursor[dst[e]], 1);
    adj[slot] = src[e];
}

__global__ void k_dinv(const int* __restrict__ deg, float* __restrict__ dinv, int N) {
    int i = blockIdx.x * 256 + threadIdx.x;
    if (i < N) dinv[i] = rsqrtf((float)(deg[i] + 1));  // +1 = self loop; always > 0
}

// ---------------- layer 1 GEMM: h0s[v] = (x[v] @ W1) * dinv[v] ----------------

__global__ void k_gemm1(const float* __restrict__ x, const float* __restrict__ W1,
                        const float* __restrict__ dinv, float* __restrict__ h0s, int N) {
    int v = blockIdx.x * 256 + threadIdx.x;
    if (v >= N) return;
    const float4* xr = (const float4*)(x + (size_t)v * F);
    float acc[H];
    #pragma unroll
    for (int j = 0; j < H; j++) acc[j] = 0.f;
    for (int k4 = 0; k4 < F / 4; k4++) {
        float4 xv = xr[k4];
        const float* w = W1 + k4 * 4 * H;   // wave-uniform address -> scalar loads
        #pragma unroll
        for (int j = 0; j < H; j++) acc[j] = fmaf(xv.x, w[j], acc[j]);
        #pragma unroll
        for (int j = 0; j < H; j++) acc[j] = fmaf(xv.y, w[H + j], acc[j]);
        #pragma unroll
        for (int j = 0; j < H; j++) acc[j] = fmaf(xv.z, w[2 * H + j], acc[j]);
        #pragma unroll
        for (int j = 0; j < H; j++) acc[j] = fmaf(xv.w, w[3 * H + j], acc[j]);
    }
    float dv = dinv[v];
    float4* o4 = (float4*)(h0s + (size_t)v * H);
    o4[0] = make_float4(acc[0] * dv, acc[1] * dv, acc[2] * dv, acc[3] * dv);
    o4[1] = make_float4(acc[4] * dv, acc[5] * dv, acc[6] * dv, acc[7] * dv);
    o4[2] = make_float4(acc[8] * dv, acc[9] * dv, acc[10] * dv, acc[11] * dv);
    o4[3] = make_float4(acc[12] * dv, acc[13] * dv, acc[14] * dv, acc[15] * dv);
}

// ---------------- CSR gather aggregation, 16 threads per node ----------------
// relu_mode=1: out = relu(dinv*acc + b1[j]) * dinv   (layer-1 epilogue, pre-scaled for layer 2)
// relu_mode=0: out = dinv*acc                        (layer-2 agg, pre-W2)

__global__ void k_agg(const float* __restrict__ hs, const int* __restrict__ rowptr,
                      const int* __restrict__ adj, const float* __restrict__ dinv,
                      const float* __restrict__ b1, float* __restrict__ out,
                      int N, int relu_mode) {
    int t = blockIdx.x * 256 + threadIdx.x;
    int n = t >> 4, j = t & 15;
    if (n >= N) return;
    int beg = rowptr[n], end = rowptr[n + 1];
    float acc = hs[(size_t)n * H + j];   // self loop (already dinv[src]-scaled)
    int e = beg;
    for (; e + 1 < end; e += 2) {
        int u0 = adj[e], u1 = adj[e + 1];
        float a0 = hs[(size_t)u0 * H + j];
        float a1 = hs[(size_t)u1 * H + j];
        acc += a0 + a1;
    }
    if (e < end) acc += hs[(size_t)adj[e] * H + j];
    float dv = dinv[n];
    float r;
    if (relu_mode) r = fmaxf(fmaf(dv, acc, b1[j]), 0.f) * dv;
    else           r = dv * acc;
    out[(size_t)n * H + j] = r;
}

// ---------------- epilogue: h2 = g2 @ W2 + b2 ; softmax ; one wave per node ----------------

__global__ void k_out(const float* __restrict__ g2, const float* __restrict__ W2,
                      const float* __restrict__ b2, float* __restrict__ dout, int N) {
    int t = blockIdx.x * 256 + threadIdx.x;
    int n = t >> 6, lane = t & 63;
    if (n >= N) return;
    const float* g = g2 + (size_t)n * H;
    float acc = 0.f;
    #pragma unroll
    for (int k = 0; k < H; k++) {
        float w = (lane < C) ? W2[k * C + lane] : 0.f;
        acc = fmaf(g[k], w, acc);
    }
    float h2 = (lane < C) ? acc + b2[lane] : -INFINITY;
    float m = h2;
    #pragma unroll
    for (int off = 32; off; off >>= 1) m = fmaxf(m, __shfl_xor(m, off, 64));
    float ex = (lane < C) ? __expf(h2 - m) : 0.f;
    float s = ex;
    #pragma unroll
    for (int off = 32; off; off >>= 1) s += __shfl_xor(s, off, 64);
    if (lane < C) {
        float inv = 1.f / s;
        dout[(size_t)n * C + lane] = ex * inv;                       // output 0: softmax
        dout[(size_t)N * C + (size_t)n * C + lane] = h2;             // output 1: logits
    }
}

extern "C" void kernel_launch(void* const* d_in, const int* in_sizes, int n_in,
                              void* d_out, int out_size, void* d_ws, size_t ws_size,
                              hipStream_t stream) {
    const float* x  = (const float*)d_in[0];
    const int*   ei = (const int*)d_in[1];
    const float* W1 = (const float*)d_in[3];
    const float* b1 = (const float*)d_in[4];
    const float* W2 = (const float*)d_in[5];
    const float* b2 = (const float*)d_in[6];
    float* out = (float*)d_out;

    int N = in_sizes[0] / F;       // 100000
    int E = in_sizes[1] / 2;       // 3200000
    const int* src = ei;
    const int* dst = ei + E;

    // workspace layout (floats/ints, all 16B-aligned: N, E divisible by 4)
    float* ws = (float*)d_ws;
    size_t o = 0;
    int* deg    = (int*)(ws + o); o += (size_t)N;
    int* rowptr = (int*)(ws + o); o += (size_t)N + 4;
    int* cursor = (int*)(ws + o); o += (size_t)N;
    int* bsum   = (int*)(ws + o); o += 1024;
    int* adj    = (int*)(ws + o); o += (size_t)E;
    float* dinv = ws + o;         o += (size_t)N;
    float* h0s  = ws + o;         o += (size_t)N * H;
    float* h1s  = ws + o;         o += (size_t)N * H;
    float* g2   = ws + o;         o += (size_t)N * H;

    int nb = (N + 255) / 256;      // 391  (<=1024 required by k_scan_b)
    int ne = (E + 255) / 256;      // 12500

    hipMemsetAsync(deg, 0, (size_t)N * sizeof(int), stream);
    k_count <<<ne, 256, 0, stream>>>(dst, deg, E);
    k_scan_a<<<nb, 256, 0, stream>>>(deg, bsum, N);
    k_scan_b<<<1, 1024, 0, stream>>>(bsum, nb, rowptr, N, E);
    k_scan_c<<<nb, 256, 0, stream>>>(deg, bsum, rowptr, cursor, N);
    k_fill  <<<ne, 256, 0, stream>>>(src, dst, cursor, adj, E);
    k_dinv  <<<nb, 256, 0, stream>>>(deg, dinv, N);
    k_gemm1 <<<nb, 256, 0, stream>>>(x, W1, dinv, h0s, N);
    k_agg   <<<(N * H + 255) / 256, 256, 0, stream>>>(h0s, rowptr, adj, dinv, b1, h1s, N, 1);
    k_agg   <<<(N * H + 255) / 256, 256, 0, stream>>>(h1s, rowptr, adj, dinv, b1, g2, N, 0);
    k_out   <<<(N * 64 + 255) / 256, 256, 0, stream>>>(g2, W2, b2, out, N);
}

// Round 2
// 849.606 us; speedup vs baseline: 1.0423x; 1.0423x over previous
//
#include <hip/hip_runtime.h>
#include <math.h>

#define F 512
#define H 16
#define C 40
#define K 4   // chains per node (depth ~8, 4-way MLP in the chase)

// ---------------- graph build: per-dst linked lists, K chains each ----------------
// nxt[] write is coalesced (indexed by e); only the atomicExch into the 1.6 MB
// head[] array is random -> no 64B-per-4B scatter amplification (was 194 MB).

__global__ void k_build(const int* __restrict__ dst, int* __restrict__ head,
                        int* __restrict__ nxt, int E) {
    int e = blockIdx.x * 256 + threadIdx.x;
    if (e >= E) return;
    int d = dst[e];
    nxt[e] = atomicExch(&head[(size_t)d * K + (e & (K - 1))], e);
}

// degree via chain walk (no atomics); 4 lanes per node, one per chain
__global__ void k_deg(const int* __restrict__ head, const int* __restrict__ nxt,
                      float* __restrict__ dinv, int N) {
    int t = blockIdx.x * 256 + threadIdx.x;
    int n = t >> 2;
    if (n >= N) return;
    int cnt = 0;
    int e = head[t];               // head[(n*K) + p], p = t&3
    while (e >= 0) { cnt++; e = nxt[e]; }
    cnt += __shfl_xor(cnt, 1, 64);
    cnt += __shfl_xor(cnt, 2, 64);
    if ((t & 3) == 0) dinv[n] = rsqrtf((float)(cnt + 1));  // +1 self loop
}

// ---------------- layer 1 GEMM: h0s[v] = (x[v] @ W1) * dinv[v] ----------------

__global__ void k_gemm1(const float* __restrict__ x, const float* __restrict__ W1,
                        const float* __restrict__ dinv, float* __restrict__ h0s, int N) {
    int v = blockIdx.x * 256 + threadIdx.x;
    if (v >= N) return;
    const float4* xr = (const float4*)(x + (size_t)v * F);
    float acc[H];
    #pragma unroll
    for (int j = 0; j < H; j++) acc[j] = 0.f;
    for (int k4 = 0; k4 < F / 4; k4++) {
        float4 xv = xr[k4];
        const float* w = W1 + k4 * 4 * H;   // wave-uniform -> scalar loads
        #pragma unroll
        for (int j = 0; j < H; j++) acc[j] = fmaf(xv.x, w[j], acc[j]);
        #pragma unroll
        for (int j = 0; j < H; j++) acc[j] = fmaf(xv.y, w[H + j], acc[j]);
        #pragma unroll
        for (int j = 0; j < H; j++) acc[j] = fmaf(xv.z, w[2 * H + j], acc[j]);
        #pragma unroll
        for (int j = 0; j < H; j++) acc[j] = fmaf(xv.w, w[3 * H + j], acc[j]);
    }
    float dv = dinv[v];
    float4* o4 = (float4*)(h0s + (size_t)v * H);
    o4[0] = make_float4(acc[0] * dv, acc[1] * dv, acc[2] * dv, acc[3] * dv);
    o4[1] = make_float4(acc[4] * dv, acc[5] * dv, acc[6] * dv, acc[7] * dv);
    o4[2] = make_float4(acc[8] * dv, acc[9] * dv, acc[10] * dv, acc[11] * dv);
    o4[3] = make_float4(acc[12] * dv, acc[13] * dv, acc[14] * dv, acc[15] * dv);
}

// ---------------- linked-list gather aggregation, 16 lanes per node ----------------
// Chase loads are wave-uniform within the 16-lane group (one transaction, broadcast);
// hs[src*16+j] is a coalesced 64B segment per group. 4 chains chased with ILP.
// relu_mode=1: out = relu(dinv*acc + b1[j]) * dinv   (layer-1 epilogue, pre-scaled)
// relu_mode=0: out = dinv*acc                        (layer-2 agg, pre-W2)

__global__ void k_agg(const float* __restrict__ hs, const int* __restrict__ head,
                      const int* __restrict__ nxt, const int* __restrict__ srcv,
                      const float* __restrict__ dinv, const float* __restrict__ b1,
                      float* __restrict__ out, int N, int relu_mode) {
    int t = blockIdx.x * 256 + threadIdx.x;
    int n = t >> 4, j = t & 15;
    if (n >= N) return;
    const int* hd = head + (size_t)n * K;
    int e0 = hd[0], e1 = hd[1], e2 = hd[2], e3 = hd[3];
    float a0 = hs[(size_t)n * H + j];   // self loop (already dinv[src]-scaled)
    float a1 = 0.f, a2 = 0.f, a3 = 0.f;
    while (e0 >= 0 || e1 >= 0 || e2 >= 0 || e3 >= 0) {
        if (e0 >= 0) { a0 += hs[(size_t)srcv[e0] * H + j]; e0 = nxt[e0]; }
        if (e1 >= 0) { a1 += hs[(size_t)srcv[e1] * H + j]; e1 = nxt[e1]; }
        if (e2 >= 0) { a2 += hs[(size_t)srcv[e2] * H + j]; e2 = nxt[e2]; }
        if (e3 >= 0) { a3 += hs[(size_t)srcv[e3] * H + j]; e3 = nxt[e3]; }
    }
    float acc = (a0 + a1) + (a2 + a3);
    float dv = dinv[n];
    float r;
    if (relu_mode) r = fmaxf(fmaf(dv, acc, b1[j]), 0.f) * dv;
    else           r = dv * acc;
    out[(size_t)n * H + j] = r;
}

// ---------------- epilogue: h2 = g2 @ W2 + b2 ; softmax ; one wave per node ----------------

__global__ void k_out(const float* __restrict__ g2, const float* __restrict__ W2,
                      const float* __restrict__ b2, float* __restrict__ dout, int N) {
    int t = blockIdx.x * 256 + threadIdx.x;
    int n = t >> 6, lane = t & 63;
    if (n >= N) return;
    const float* g = g2 + (size_t)n * H;
    float acc = 0.f;
    #pragma unroll
    for (int k = 0; k < H; k++) {
        float w = (lane < C) ? W2[k * C + lane] : 0.f;
        acc = fmaf(g[k], w, acc);
    }
    float h2 = (lane < C) ? acc + b2[lane] : -INFINITY;
    float m = h2;
    #pragma unroll
    for (int off = 32; off; off >>= 1) m = fmaxf(m, __shfl_xor(m, off, 64));
    float ex = (lane < C) ? __expf(h2 - m) : 0.f;
    float s = ex;
    #pragma unroll
    for (int off = 32; off; off >>= 1) s += __shfl_xor(s, off, 64);
    if (lane < C) {
        float inv = 1.f / s;
        dout[(size_t)n * C + lane] = ex * inv;                       // output 0: softmax
        dout[(size_t)N * C + (size_t)n * C + lane] = h2;             // output 1: logits
    }
}

extern "C" void kernel_launch(void* const* d_in, const int* in_sizes, int n_in,
                              void* d_out, int out_size, void* d_ws, size_t ws_size,
                              hipStream_t stream) {
    const float* x  = (const float*)d_in[0];
    const int*   ei = (const int*)d_in[1];
    const float* W1 = (const float*)d_in[3];
    const float* b1 = (const float*)d_in[4];
    const float* W2 = (const float*)d_in[5];
    const float* b2 = (const float*)d_in[6];
    float* out = (float*)d_out;

    int N = in_sizes[0] / F;       // 100000
    int E = in_sizes[1] / 2;       // 3200000
    const int* src = ei;
    const int* dst = ei + E;

    // workspace layout
    float* ws = (float*)d_ws;
    size_t o = 0;
    int* head   = (int*)(ws + o); o += (size_t)N * K;
    int* nxt    = (int*)(ws + o); o += (size_t)E;
    float* dinv = ws + o;         o += (size_t)N;
    float* h0s  = ws + o;         o += (size_t)N * H;
    float* h1s  = ws + o;         o += (size_t)N * H;
    float* g2   = ws + o;         o += (size_t)N * H;

    int nb = (N + 255) / 256;
    int ne = (E + 255) / 256;

    hipMemsetAsync(head, 0xFF, (size_t)N * K * sizeof(int), stream);  // head = -1
    k_build <<<ne, 256, 0, stream>>>(dst, head, nxt, E);
    k_deg   <<<(N * K + 255) / 256, 256, 0, stream>>>(head, nxt, dinv, N);
    k_gemm1 <<<nb, 256, 0, stream>>>(x, W1, dinv, h0s, N);
    k_agg   <<<(N * H + 255) / 256, 256, 0, stream>>>(h0s, head, nxt, src, dinv, b1, h1s, N, 1);
    k_agg   <<<(N * H + 255) / 256, 256, 0, stream>>>(h1s, head, nxt, src, dinv, b1, g2, N, 0);
    k_out   <<<(N * 64 + 255) / 256, 256, 0, stream>>>(g2, W2, b2, out, N);
}